// Round 10
// baseline (226.738 us; speedup 1.0000x reference)
//
#include <hip/hip_runtime.h>
#include <stdint.h>

#define NH 16
#define NDV 64
#define NDM 1024
#define NB 8
#define NL 1024

typedef __attribute__((ext_vector_type(8))) short short8;
typedef __attribute__((ext_vector_type(4))) short short4v;
typedef __attribute__((ext_vector_type(4))) float f32x4;

static __device__ __forceinline__ unsigned short f2bf(float x) {
    unsigned int u = __builtin_bit_cast(unsigned int, x);
    unsigned int r = (u + 0x7fffu + ((u >> 16) & 1u)) >> 16;
    return (unsigned short)r;
}

static __device__ __forceinline__ float waveMax(float v) {
#pragma unroll
    for (int o = 32; o > 0; o >>= 1) v = fmaxf(v, __shfl_xor(v, o, 64));
    return v;
}
static __device__ __forceinline__ float waveSum(float v) {
#pragma unroll
    for (int o = 32; o > 0; o >>= 1) v += __shfl_xor(v, o, 64);
    return v;
}

// async global->LDS, 16B per lane (wave writes 1KB contiguous at ldsptr)
static __device__ __forceinline__ void gload_lds16(const void* g, void* l) {
    __builtin_amdgcn_global_load_lds((const __attribute__((address_space(1))) void*)g,
                                     (__attribute__((address_space(3))) void*)l, 16, 0, 0);
}

// ---------------- phase A: softmax+replicate (fp32 out + bf16) + converts ----------------
__global__ __launch_bounds__(256) void phaseA(
    const float* __restrict__ posi, float* __restrict__ attn_out,
    unsigned short* __restrict__ a_bf,
    const float* __restrict__ v, const float* __restrict__ wv, const float* __restrict__ wfc,
    unsigned short* __restrict__ v_bf, unsigned short* __restrict__ wv_bf,
    unsigned short* __restrict__ wfc_bf) {
    __shared__ float red[8];
    const int bid = blockIdx.x;
    const int t = threadIdx.x;
    if (bid < 16384) {
        const int h = bid >> 10, i = bid & 1023;
        const float4* rowp = (const float4*)(posi + (((size_t)h << 10) + i) * 1024);
        float4 p = rowp[t];
        const int j0 = t << 2;
        float* pf = (float*)&p;
        if (i >= j0 && i < j0 + 4) pf[i - j0] = -1e30f;  // mask diagonal
        float m = fmaxf(fmaxf(pf[0], pf[1]), fmaxf(pf[2], pf[3]));
        m = waveMax(m);
        if ((t & 63) == 0) red[t >> 6] = m;
        __syncthreads();
        m = fmaxf(fmaxf(red[0], red[1]), fmaxf(red[2], red[3]));
        const float e0 = __expf(pf[0] - m), e1 = __expf(pf[1] - m);
        const float e2 = __expf(pf[2] - m), e3 = __expf(pf[3] - m);
        float s = waveSum(e0 + e1 + e2 + e3);
        if ((t & 63) == 0) red[4 + (t >> 6)] = s;
        __syncthreads();
        s = red[4] + red[5] + red[6] + red[7];
        const float inv = 1.0f / s;
        f32x4 a;
        a[0] = e0 * inv; a[1] = e1 * inv; a[2] = e2 * inv; a[3] = e3 * inv;
        float* base = attn_out + (((size_t)(h << 3)) << 20) + ((size_t)i << 10);
#pragma unroll
        for (int b = 0; b < 8; ++b)
            __builtin_nontemporal_store(a, (f32x4*)(base + ((size_t)b << 20)) + t);
        short4v u;
        u[0] = (short)f2bf(a[0]); u[1] = (short)f2bf(a[1]);
        u[2] = (short)f2bf(a[2]); u[3] = (short)f2bf(a[3]);
        *(short4v*)(a_bf + ((((size_t)h << 10) + i) << 10) + j0) = u;
    } else {
        int b = bid - 16384;
        const float* src;
        unsigned short* dst;
        if (b < 8192)      { src = v;   dst = v_bf; }
        else if (b < 9216) { src = wv;  dst = wv_bf;  b -= 8192; }
        else               { src = wfc; dst = wfc_bf; b -= 9216; }
        const size_t idx = ((size_t)b * 256 + t) << 2;
        const float4 x = *(const float4*)(src + idx);
        short4v u;
        u[0] = (short)f2bf(x.x); u[1] = (short)f2bf(x.y);
        u[2] = (short)f2bf(x.z); u[3] = (short)f2bf(x.w);
        *(short4v*)(dst + idx) = u;
    }
}

// ---------------- 128x128 MFMA GEMM core, BK=32, QUAD-buffered, depth-3 counted vmcnt ----------------
// C = A[M,K] @ Bt[N,K]^T. 32 rounds of {vmcnt(8): own stage t landed, t+1/t+2 flying;
// s_barrier; issue stage t+3 into buf[(t+3)&3] (freed by round t-1); 4+4 ds_read_b128;
// 16 MFMA}. ~12 loads/wave in flight during compute -> ~96KB/CU at 2 blocks.
template <int EPI>
static __device__ __forceinline__ void gemm128_core(
    const unsigned short* __restrict__ A,
    const unsigned short* __restrict__ Bt,
    const float* __restrict__ bias,
    void* __restrict__ Cout,
    const int K, const int tm, const int tn, const int bh,
    unsigned short* sA, unsigned short* sB) {  // each 4*4096 shorts (32KB)
    const int tid = threadIdx.x;
    const int lane = tid & 63;
    const int w = tid >> 6;
    const int wr = w >> 1, wc = w & 1;

    const unsigned short* Ab = A + (size_t)tm * 128 * K;
    const unsigned short* Bb = Bt + (size_t)tn * 128 * K;

    // staging: wave w covers rows [w*32, w*32+32); lane -> rows r0, r0+16; chunk = lane&3
    const int r0 = w * 32 + (lane >> 2);
    const int ch = lane & 3;
    const int so = ((ch ^ ((r0 >> 1) & 3)) << 3);  // pre-swizzled source col (shorts)
    const unsigned short* gA0 = Ab + (size_t)r0 * K + so;
    const unsigned short* gA1 = Ab + (size_t)(r0 + 16) * K + so;  // same swizzle key
    const unsigned short* gB0 = Bb + (size_t)r0 * K + so;
    const unsigned short* gB1 = Bb + (size_t)(r0 + 16) * K + so;
    const int ldsOff = w * 1024;

    // fragment ds_read offsets (swizzled), within one buffer
    const int c = lane >> 4;
    int offA[4], offB[4];
#pragma unroll
    for (int f = 0; f < 4; ++f) {
        const int fra = wr * 64 + f * 16 + (lane & 15);
        offA[f] = fra * 32 + ((c ^ ((fra >> 1) & 3)) << 3);
        const int frb = wc * 64 + f * 16 + (lane & 15);
        offB[f] = frb * 32 + ((c ^ ((frb >> 1) & 3)) << 3);
    }

    f32x4 acc[4][4];
#pragma unroll
    for (int i = 0; i < 4; ++i)
#pragma unroll
        for (int j = 0; j < 4; ++j) acc[i][j] = (f32x4){0.f, 0.f, 0.f, 0.f};

    const int nst = K >> 5;  // BK=32 rounds

#define STAGE32(buf, kt)                                      \
    {                                                         \
        unsigned short* lA = sA + ((buf) << 12) + ldsOff;     \
        unsigned short* lB = sB + ((buf) << 12) + ldsOff;     \
        gload_lds16(gA0 + (kt), lA);                          \
        gload_lds16(gA1 + (kt), lA + 512);                    \
        gload_lds16(gB0 + (kt), lB);                          \
        gload_lds16(gB1 + (kt), lB + 512);                    \
    }

    // prologue: stage rounds 0,1,2 into buffers 0,1,2
    STAGE32(0, 0)
    STAGE32(1, 32)
    STAGE32(2, 64)

    for (int t = 0; t < nst; ++t) {
        // wait until own stage-t loads have landed (stages t+1, t+2 keep flying)
        if (t + 2 < nst) {
            asm volatile("s_waitcnt vmcnt(8)" ::: "memory");
        } else if (t + 1 < nst) {
            asm volatile("s_waitcnt vmcnt(4)" ::: "memory");
        } else {
            asm volatile("s_waitcnt vmcnt(0)" ::: "memory");
        }
        __builtin_amdgcn_s_barrier();        // all waves' stage t landed; round t-1 compute done
        __builtin_amdgcn_sched_barrier(0);
        if (t + 3 < nst) {                   // stage t+3 into buf freed by round t-1
            STAGE32((t + 3) & 3, (t + 3) << 5)
        }
        const unsigned short* bA = sA + ((t & 3) << 12);
        const unsigned short* bB = sB + ((t & 3) << 12);
        short8 af[4], bfv[4];
#pragma unroll
        for (int f = 0; f < 4; ++f) af[f] = *(const short8*)&bA[offA[f]];
#pragma unroll
        for (int f = 0; f < 4; ++f) bfv[f] = *(const short8*)&bB[offB[f]];
        __builtin_amdgcn_s_setprio(1);
#pragma unroll
        for (int i = 0; i < 4; ++i)
#pragma unroll
            for (int j = 0; j < 4; ++j)
                acc[i][j] = __builtin_amdgcn_mfma_f32_16x16x32_bf16(af[i], bfv[j], acc[i][j], 0, 0, 0);
        __builtin_amdgcn_s_setprio(0);
    }
#undef STAGE32

#pragma unroll
    for (int i = 0; i < 4; ++i) {
        const int gRow0 = tm * 128 + wr * 64 + i * 16 + ((lane >> 4) << 2);
#pragma unroll
        for (int j = 0; j < 4; ++j) {
            const int gCol = tn * 128 + wc * 64 + j * 16 + (lane & 15);
            f32x4 v = acc[i][j];
            if (EPI == 1) {
                const float bb2 = bias[gCol];
                const int hh = gCol >> 6, dd = gCol & 63;
                const int b = gRow0 >> 10, ll2 = gRow0 & 1023;
                unsigned short* C = (unsigned short*)Cout;
                short4v u;
                u[0] = (short)f2bf(v[0] + bb2);
                u[1] = (short)f2bf(v[1] + bb2);
                u[2] = (short)f2bf(v[2] + bb2);
                u[3] = (short)f2bf(v[3] + bb2);
                *(short4v*)(C + (size_t)hh * 524288 + ((size_t)b * 64 + dd) * 1024 + ll2) = u;
            } else if (EPI == 2) {
                const int b = gCol >> 6, dd = gCol & 63;
                unsigned short* X = (unsigned short*)Cout;
#pragma unroll
                for (int r = 0; r < 4; ++r)
                    X[((size_t)b * 1024 + gRow0 + r) * 1024 + bh * 64 + dd] = f2bf(v[r]);
            } else {
                const float bb2 = bias[gCol];
                float* O = (float*)Cout;
#pragma unroll
                for (int r = 0; r < 4; ++r)
                    O[(size_t)(gRow0 + r) * 1024 + gCol] = v[r] + bb2;
            }
        }
    }
}

// ---------------- GEMM wrappers (XCD-swizzled block id, 512 = 8 x 64) ----------------
__global__ __launch_bounds__(256) void gemm_k1(const unsigned short* __restrict__ A,
                                               const unsigned short* __restrict__ Bt,
                                               const float* __restrict__ bias,
                                               unsigned short* __restrict__ C) {
    __shared__ unsigned short sA[16384], sB[16384];
    const int s = (blockIdx.x & 7) * 64 + (blockIdx.x >> 3);
    gemm128_core<1>(A, Bt, bias, C, 1024, s >> 3, s & 7, 0, sA, sB);
}

__global__ __launch_bounds__(256) void gemm_k2(const unsigned short* __restrict__ A,
                                               const unsigned short* __restrict__ Bt,
                                               unsigned short* __restrict__ X) {
    __shared__ unsigned short sA[16384], sB[16384];
    const int s = (blockIdx.x & 7) * 64 + (blockIdx.x >> 3);
    const int bh = s >> 5;
    gemm128_core<2>(A + (size_t)bh * 1048576, Bt + (size_t)bh * 524288, nullptr, X,
                    1024, (s >> 2) & 7, s & 3, bh, sA, sB);
}

__global__ __launch_bounds__(256) void gemm_k3(const unsigned short* __restrict__ A,
                                               const unsigned short* __restrict__ Bt,
                                               const float* __restrict__ bias,
                                               float* __restrict__ O) {
    __shared__ unsigned short sA[16384], sB[16384];
    const int s = (blockIdx.x & 7) * 64 + (blockIdx.x >> 3);
    gemm128_core<3>(A, Bt, bias, O, 1024, s >> 3, s & 7, 0, sA, sB);
}

// ---------------- in-place row LayerNorm over DM=1024 ----------------
__global__ __launch_bounds__(256) void ln_kernel(float* __restrict__ out,
                                                 const float* __restrict__ g,
                                                 const float* __restrict__ b) {
    __shared__ float red[8];
    const int row = blockIdx.x, t = threadIdx.x;
    float4* p = (float4*)(out + ((size_t)row << 10));
    float4 x = p[t];
    float s = x.x + x.y + x.z + x.w;
    float sq = x.x * x.x + x.y * x.y + x.z * x.z + x.w * x.w;
    s = waveSum(s);
    sq = waveSum(sq);
    if ((t & 63) == 0) { red[t >> 6] = s; red[4 + (t >> 6)] = sq; }
    __syncthreads();
    s = red[0] + red[1] + red[2] + red[3];
    sq = red[4] + red[5] + red[6] + red[7];
    const float mu = s * (1.f / 1024.f);
    const float var = sq * (1.f / 1024.f) - mu * mu;
    const float rinv = rsqrtf(var + 1e-5f);
    const float4 gg = ((const float4*)g)[t];
    const float4 bb = ((const float4*)b)[t];
    x.x = (x.x - mu) * rinv * gg.x + bb.x;
    x.y = (x.y - mu) * rinv * gg.y + bb.y;
    x.z = (x.z - mu) * rinv * gg.z + bb.z;
    x.w = (x.w - mu) * rinv * gg.w + bb.w;
    p[t] = x;
}

extern "C" void kernel_launch(void* const* d_in, const int* in_sizes, int n_in,
                              void* d_out, int out_size, void* d_ws, size_t ws_size,
                              hipStream_t stream) {
    const float* v    = (const float*)d_in[2];
    const float* posi = (const float*)d_in[3];
    const float* w_v  = (const float*)d_in[6];
    const float* b_v  = (const float*)d_in[7];
    const float* w_fc = (const float*)d_in[8];
    const float* b_fc = (const float*)d_in[9];
    const float* ln_g = (const float*)d_in[10];
    const float* ln_b = (const float*)d_in[11];

    float* out = (float*)d_out;                     // [8,1024,1024] fp32
    float* attn_out = out + (size_t)NB * NL * NDM;  // [128,1024,1024] fp32

    char* ws = (char*)d_ws;
    unsigned short* A_bf   = (unsigned short*)(ws);              // [16][1024][1024] bf16  32MB
    unsigned short* v_bf   = (unsigned short*)(ws + 33554432);   // [8192][1024]     bf16  16MB
    unsigned short* wv_bf  = (unsigned short*)(ws + 50331648);   // [1024][1024]     bf16   2MB
    unsigned short* wfc_bf = (unsigned short*)(ws + 52428800);   // [1024][1024]     bf16   2MB
    unsigned short* vvT    = (unsigned short*)(ws + 54525952);   // [16][512][1024]  bf16  16MB
    unsigned short* X      = (unsigned short*)(ws + 71303168);   // [8192][1024]     bf16  16MB

    // softmax -> attn fp32 (x8, nontemporal) + A_bf, plus bf16 converts
    phaseA<<<26624, 256, 0, stream>>>(posi, attn_out, A_bf, v, w_v, w_fc, v_bf, wv_bf, wfc_bf);
    // gemm1: vvT[h][b*64+d][l] = (v@w_v^T+b_v)^T
    gemm_k1<<<512, 256, 0, stream>>>(v_bf, wv_bf, b_v, vvT);
    // gemm2: X[(b*1024+q)][h*64+d] = A[h]@vvT[h]^T
    gemm_k2<<<512, 256, 0, stream>>>(A_bf, vvT, X);
    // gemm3: out = X@w_fc^T + b_fc (fp32)
    gemm_k3<<<512, 256, 0, stream>>>(X, wfc_bf, b_fc, out);
    ln_kernel<<<8192, 256, 0, stream>>>(out, ln_g, ln_b);
}

// Round 11
// 225.595 us; speedup vs baseline: 1.0051x; 1.0051x over previous
//
#include <hip/hip_runtime.h>
#include <stdint.h>

#define NH 16
#define NDV 64
#define NDM 1024
#define NB 8
#define NL 1024

typedef __attribute__((ext_vector_type(8))) short short8;
typedef __attribute__((ext_vector_type(4))) short short4v;
typedef __attribute__((ext_vector_type(4))) float f32x4;

static __device__ __forceinline__ unsigned short f2bf(float x) {
    unsigned int u = __builtin_bit_cast(unsigned int, x);
    unsigned int r = (u + 0x7fffu + ((u >> 16) & 1u)) >> 16;
    return (unsigned short)r;
}

static __device__ __forceinline__ float waveMax(float v) {
#pragma unroll
    for (int o = 32; o > 0; o >>= 1) v = fmaxf(v, __shfl_xor(v, o, 64));
    return v;
}
static __device__ __forceinline__ float waveSum(float v) {
#pragma unroll
    for (int o = 32; o > 0; o >>= 1) v += __shfl_xor(v, o, 64);
    return v;
}

// async global->LDS, 16B per lane (wave writes 1KB contiguous at ldsptr)
static __device__ __forceinline__ void gload_lds16(const void* g, void* l) {
    __builtin_amdgcn_global_load_lds((const __attribute__((address_space(1))) void*)g,
                                     (__attribute__((address_space(3))) void*)l, 16, 0, 0);
}

// ---------------- phase A: softmax (b=0 slice + bf16) + converts ----------------
__global__ __launch_bounds__(256) void phaseA(
    const float* __restrict__ posi, float* __restrict__ attn_out,
    unsigned short* __restrict__ a_bf,
    const float* __restrict__ v, const float* __restrict__ wv, const float* __restrict__ wfc,
    unsigned short* __restrict__ v_bf, unsigned short* __restrict__ wv_bf,
    unsigned short* __restrict__ wfc_bf) {
    __shared__ float red[8];
    const int bid = blockIdx.x;
    const int t = threadIdx.x;
    if (bid < 16384) {
        const int h = bid >> 10, i = bid & 1023;
        const float4* rowp = (const float4*)(posi + (((size_t)h << 10) + i) * 1024);
        float4 p = rowp[t];
        const int j0 = t << 2;
        float* pf = (float*)&p;
        if (i >= j0 && i < j0 + 4) pf[i - j0] = -1e30f;  // mask diagonal
        float m = fmaxf(fmaxf(pf[0], pf[1]), fmaxf(pf[2], pf[3]));
        m = waveMax(m);
        if ((t & 63) == 0) red[t >> 6] = m;
        __syncthreads();
        m = fmaxf(fmaxf(red[0], red[1]), fmaxf(red[2], red[3]));
        const float e0 = __expf(pf[0] - m), e1 = __expf(pf[1] - m);
        const float e2 = __expf(pf[2] - m), e3 = __expf(pf[3] - m);
        float s = waveSum(e0 + e1 + e2 + e3);
        if ((t & 63) == 0) red[4 + (t >> 6)] = s;
        __syncthreads();
        s = red[4] + red[5] + red[6] + red[7];
        const float inv = 1.0f / s;
        f32x4 a;
        a[0] = e0 * inv; a[1] = e1 * inv; a[2] = e2 * inv; a[3] = e3 * inv;
        // write ONLY the b=0 slice (cache-resident: re-read by rep waves soon)
        float* base = attn_out + (((size_t)(h << 3)) << 20) + ((size_t)i << 10);
        ((f32x4*)base)[t] = a;
        short4v u;
        u[0] = (short)f2bf(a[0]); u[1] = (short)f2bf(a[1]);
        u[2] = (short)f2bf(a[2]); u[3] = (short)f2bf(a[3]);
        *(short4v*)(a_bf + ((((size_t)h << 10) + i) << 10) + j0) = u;
    } else {
        int b = bid - 16384;
        const float* src;
        unsigned short* dst;
        if (b < 8192)      { src = v;   dst = v_bf; }
        else if (b < 9216) { src = wv;  dst = wv_bf;  b -= 8192; }
        else               { src = wfc; dst = wfc_bf; b -= 9216; }
        const size_t idx = ((size_t)b * 256 + t) << 2;
        const float4 x = *(const float4*)(src + idx);
        short4v u;
        u[0] = (short)f2bf(x.x); u[1] = (short)f2bf(x.y);
        u[2] = (short)f2bf(x.z); u[3] = (short)f2bf(x.w);
        *(short4v*)(dst + idx) = u;
    }
}

// ---------------- 128x128 MFMA GEMM core, BK=64, double-buffered, counted vmcnt ----------------
// Exactly the r9 winner: 16 rounds x { barrierA; stage t+1; vmcnt(8); barrierB; 2x(8 ds_read + 16 MFMA) }.
// 32 s_barrier calls total -- rep waves must match this count exactly.
template <int EPI>
static __device__ __forceinline__ void gemm128_core(
    const unsigned short* __restrict__ A,
    const unsigned short* __restrict__ Bt,
    const float* __restrict__ bias,
    void* __restrict__ Cout,
    const int K, const int tm, const int tn, const int bh,
    unsigned short* sA, unsigned short* sB) {  // each 2*8192 shorts (32KB)
    const int tid = threadIdx.x;   // < 256 here
    const int lane = tid & 63;
    const int w = tid >> 6;
    const int wr = w >> 1, wc = w & 1;

    const unsigned short* Ab = A + (size_t)tm * 128 * K;
    const unsigned short* Bb = Bt + (size_t)tn * 128 * K;

    const int lrow = lane >> 3;
    const int lch = lane & 7;

    int offA[2][4], offB[2][4];
#pragma unroll
    for (int ks = 0; ks < 2; ++ks)
#pragma unroll
        for (int f = 0; f < 4; ++f) {
            const int fra = wr * 64 + f * 16 + (lane & 15);
            offA[ks][f] = fra * 64 + ((ks * 4 + (lane >> 4)) ^ (fra & 7)) * 8;
            const int frb = wc * 64 + f * 16 + (lane & 15);
            offB[ks][f] = frb * 64 + ((ks * 4 + (lane >> 4)) ^ (frb & 7)) * 8;
        }

    f32x4 acc[4][4];
#pragma unroll
    for (int i = 0; i < 4; ++i)
#pragma unroll
        for (int j = 0; j < 4; ++j) acc[i][j] = (f32x4){0.f, 0.f, 0.f, 0.f};

    const int nst = K >> 6;  // 16 rounds

#define STAGE64(buf, kt)                                                          \
    {                                                                             \
        unsigned short* dA = sA + ((buf) << 13);                                  \
        unsigned short* dB = sB + ((buf) << 13);                                  \
        _Pragma("unroll")                                                         \
        for (int g = 0; g < 4; ++g) {                                             \
            const int row = w * 32 + g * 8 + lrow;                                \
            const int sc = ((lch ^ (row & 7)) << 3);                              \
            gload_lds16(Ab + (size_t)row * K + (kt) + sc, dA + (w * 32 + g * 8) * 64); \
            gload_lds16(Bb + (size_t)row * K + (kt) + sc, dB + (w * 32 + g * 8) * 64); \
        }                                                                         \
    }

    STAGE64(0, 0)

    for (int t = 0; t < nst; ++t) {
        __builtin_amdgcn_s_barrier();            // A
        __builtin_amdgcn_sched_barrier(0);
        if (t + 1 < nst) {
            STAGE64((t + 1) & 1, (t + 1) << 6)
            asm volatile("s_waitcnt vmcnt(8)" ::: "memory");
        } else {
            asm volatile("s_waitcnt vmcnt(0)" ::: "memory");
        }
        __builtin_amdgcn_s_barrier();            // B
        __builtin_amdgcn_sched_barrier(0);
        const unsigned short* bA = sA + ((t & 1) << 13);
        const unsigned short* bB = sB + ((t & 1) << 13);
#pragma unroll
        for (int ks = 0; ks < 2; ++ks) {
            short8 af[4], bfv[4];
#pragma unroll
            for (int f = 0; f < 4; ++f) af[f] = *(const short8*)&bA[offA[ks][f]];
#pragma unroll
            for (int f = 0; f < 4; ++f) bfv[f] = *(const short8*)&bB[offB[ks][f]];
            __builtin_amdgcn_s_setprio(1);
#pragma unroll
            for (int i = 0; i < 4; ++i)
#pragma unroll
                for (int j = 0; j < 4; ++j)
                    acc[i][j] = __builtin_amdgcn_mfma_f32_16x16x32_bf16(af[i], bfv[j], acc[i][j], 0, 0, 0);
            __builtin_amdgcn_s_setprio(0);
        }
    }
#undef STAGE64

#pragma unroll
    for (int i = 0; i < 4; ++i) {
        const int gRow0 = tm * 128 + wr * 64 + i * 16 + ((lane >> 4) << 2);
#pragma unroll
        for (int j = 0; j < 4; ++j) {
            const int gCol = tn * 128 + wc * 64 + j * 16 + (lane & 15);
            f32x4 v = acc[i][j];
            if (EPI == 1) {
                const float bb2 = bias[gCol];
                const int hh = gCol >> 6, dd = gCol & 63;
                const int b = gRow0 >> 10, ll2 = gRow0 & 1023;
                unsigned short* C = (unsigned short*)Cout;
                short4v u;
                u[0] = (short)f2bf(v[0] + bb2);
                u[1] = (short)f2bf(v[1] + bb2);
                u[2] = (short)f2bf(v[2] + bb2);
                u[3] = (short)f2bf(v[3] + bb2);
                *(short4v*)(C + (size_t)hh * 524288 + ((size_t)b * 64 + dd) * 1024 + ll2) = u;
            } else if (EPI == 2) {
                const int b = gCol >> 6, dd = gCol & 63;
                unsigned short* X = (unsigned short*)Cout;
#pragma unroll
                for (int r = 0; r < 4; ++r)
                    X[((size_t)b * 1024 + gRow0 + r) * 1024 + bh * 64 + dd] = f2bf(v[r]);
            } else {
                const float bb2 = bias[gCol];
                float* O = (float*)Cout;
#pragma unroll
                for (int r = 0; r < 4; ++r)
                    O[(size_t)(gRow0 + r) * 1024 + gCol] = v[r] + bb2;
            }
        }
    }
}

// ---------------- rep waves: replicate attn b=0 slice to b=1..7 ----------------
// Runs on waves 4-5 (128 lanes). MUST execute exactly 32 s_barrier calls (16 rounds x2)
// to pair with gemm128_core's barriers. Row copy double-buffered across rounds.
static __device__ __forceinline__ void rep_waves(float* __restrict__ attn_out,
                                                 int row0, int nrows) {
    const int l2 = threadIdx.x - 256;  // 0..127
    f32x4 c0 = {0.f, 0.f, 0.f, 0.f}, c1 = c0;
    if (nrows > 0) {
        const int rr = row0;
        const float* src = attn_out + (((size_t)((rr >> 10) << 3)) << 20) + ((size_t)(rr & 1023) << 10);
        c0 = ((const f32x4*)src)[l2];
        c1 = ((const f32x4*)src)[l2 + 128];
    }
    for (int t = 0; t < 16; ++t) {
        __builtin_amdgcn_s_barrier();            // pairs with gemm barrier A
        f32x4 n0 = c0, n1 = c1;
        if (t + 1 < nrows) {
            const int rr = row0 + t + 1;
            const float* src = attn_out + (((size_t)((rr >> 10) << 3)) << 20) + ((size_t)(rr & 1023) << 10);
            n0 = ((const f32x4*)src)[l2];
            n1 = ((const f32x4*)src)[l2 + 128];
        }
        if (t < nrows) {
            const int rr = row0 + t;
            float* dst = attn_out + (((size_t)((rr >> 10) << 3)) << 20) + ((size_t)(rr & 1023) << 10);
#pragma unroll
            for (int b = 1; b < 8; ++b) {
                __builtin_nontemporal_store(c0, (f32x4*)(dst + ((size_t)b << 20)) + l2);
                __builtin_nontemporal_store(c1, (f32x4*)(dst + ((size_t)b << 20)) + l2 + 128);
            }
        }
        __builtin_amdgcn_s_barrier();            // pairs with gemm barrier B
        c0 = n0; c1 = n1;
    }
    // gemm epilogue has no barriers -> rep waves may simply exit
}

// ---------------- fused gemm + replicate kernels: 384 threads (4 gemm waves + 2 rep waves) ----------------
template <int EPI>
__global__ __launch_bounds__(384, 3) void gemm_rep(
    const unsigned short* __restrict__ A, const unsigned short* __restrict__ Bt,
    const float* __restrict__ bias, void* __restrict__ Cout,
    float* __restrict__ attn_out, int repBase, int repPerBlk) {
    __shared__ unsigned short sA[16384], sB[16384];
    if (threadIdx.x < 256) {
        const int s = (blockIdx.x & 7) * 64 + (blockIdx.x >> 3);  // XCD swizzle
        if (EPI == 2) {
            const int bh = s >> 5;
            gemm128_core<2>(A + (size_t)bh * 1048576, Bt + (size_t)bh * 524288, bias, Cout,
                            1024, (s >> 2) & 7, s & 3, bh, sA, sB);
        } else {
            gemm128_core<EPI>(A, Bt, bias, Cout, 1024, s >> 3, s & 7, 0, sA, sB);
        }
    } else {
        rep_waves(attn_out, repBase + blockIdx.x * repPerBlk, repPerBlk);
    }
}

// ---------------- in-place row LayerNorm over DM=1024 ----------------
__global__ __launch_bounds__(256) void ln_kernel(float* __restrict__ out,
                                                 const float* __restrict__ g,
                                                 const float* __restrict__ b) {
    __shared__ float red[8];
    const int row = blockIdx.x, t = threadIdx.x;
    float4* p = (float4*)(out + ((size_t)row << 10));
    float4 x = p[t];
    float s = x.x + x.y + x.z + x.w;
    float sq = x.x * x.x + x.y * x.y + x.z * x.z + x.w * x.w;
    s = waveSum(s);
    sq = waveSum(sq);
    if ((t & 63) == 0) { red[t >> 6] = s; red[4 + (t >> 6)] = sq; }
    __syncthreads();
    s = red[0] + red[1] + red[2] + red[3];
    sq = red[4] + red[5] + red[6] + red[7];
    const float mu = s * (1.f / 1024.f);
    const float var = sq * (1.f / 1024.f) - mu * mu;
    const float rinv = rsqrtf(var + 1e-5f);
    const float4 gg = ((const float4*)g)[t];
    const float4 bb = ((const float4*)b)[t];
    x.x = (x.x - mu) * rinv * gg.x + bb.x;
    x.y = (x.y - mu) * rinv * gg.y + bb.y;
    x.z = (x.z - mu) * rinv * gg.z + bb.z;
    x.w = (x.w - mu) * rinv * gg.w + bb.w;
    p[t] = x;
}

extern "C" void kernel_launch(void* const* d_in, const int* in_sizes, int n_in,
                              void* d_out, int out_size, void* d_ws, size_t ws_size,
                              hipStream_t stream) {
    const float* v    = (const float*)d_in[2];
    const float* posi = (const float*)d_in[3];
    const float* w_v  = (const float*)d_in[6];
    const float* b_v  = (const float*)d_in[7];
    const float* w_fc = (const float*)d_in[8];
    const float* b_fc = (const float*)d_in[9];
    const float* ln_g = (const float*)d_in[10];
    const float* ln_b = (const float*)d_in[11];

    float* out = (float*)d_out;                     // [8,1024,1024] fp32
    float* attn_out = out + (size_t)NB * NL * NDM;  // [128,1024,1024] fp32

    char* ws = (char*)d_ws;
    unsigned short* A_bf   = (unsigned short*)(ws);              // [16][1024][1024] bf16  32MB
    unsigned short* v_bf   = (unsigned short*)(ws + 33554432);   // [8192][1024]     bf16  16MB
    unsigned short* wv_bf  = (unsigned short*)(ws + 50331648);   // [1024][1024]     bf16   2MB
    unsigned short* wfc_bf = (unsigned short*)(ws + 52428800);   // [1024][1024]     bf16   2MB
    unsigned short* vvT    = (unsigned short*)(ws + 54525952);   // [16][512][1024]  bf16  16MB
    unsigned short* X      = (unsigned short*)(ws + 71303168);   // [8192][1024]     bf16  16MB

    // softmax -> A_bf + attn b=0 slice, plus bf16 converts
    phaseA<<<26624, 256, 0, stream>>>(posi, attn_out, A_bf, v, w_v, w_fc, v_bf, wv_bf, wfc_bf);
    // gemm1: vvT = (v@w_v^T+b_v)^T            | + replicate rows [0, 5632)    (11/blk)
    gemm_rep<1><<<512, 384, 0, stream>>>(v_bf, wv_bf, b_v, vvT, attn_out, 0, 11);
    // gemm2: X = A[h]@vvT[h]^T                | + replicate rows [5632, 11264) (11/blk)
    gemm_rep<2><<<512, 384, 0, stream>>>(A_bf, vvT, nullptr, X, attn_out, 5632, 11);
    // gemm3: out = X@w_fc^T + b_fc (fp32)     | + replicate rows [11264, 16384) (10/blk)
    gemm_rep<3><<<512, 384, 0, stream>>>(X, wfc_bf, b_fc, out, attn_out, 11264, 10);
    ln_kernel<<<8192, 256, 0, stream>>>(out, ln_g, ln_b);
}

// Round 12
// 210.075 us; speedup vs baseline: 1.0793x; 1.0739x over previous
//
#include <hip/hip_runtime.h>
#include <stdint.h>

#define NH 16
#define NDV 64
#define NDM 1024
#define NB 8
#define NL 1024

typedef __attribute__((ext_vector_type(8))) short short8;
typedef __attribute__((ext_vector_type(4))) short short4v;
typedef __attribute__((ext_vector_type(4))) float f32x4;

static __device__ __forceinline__ unsigned short f2bf(float x) {
    unsigned int u = __builtin_bit_cast(unsigned int, x);
    unsigned int r = (u + 0x7fffu + ((u >> 16) & 1u)) >> 16;
    return (unsigned short)r;
}

static __device__ __forceinline__ float waveMax(float v) {
#pragma unroll
    for (int o = 32; o > 0; o >>= 1) v = fmaxf(v, __shfl_xor(v, o, 64));
    return v;
}
static __device__ __forceinline__ float waveSum(float v) {
#pragma unroll
    for (int o = 32; o > 0; o >>= 1) v += __shfl_xor(v, o, 64);
    return v;
}

// async global->LDS, 16B per lane (wave writes 1KB contiguous at ldsptr)
static __device__ __forceinline__ void gload_lds16(const void* g, void* l) {
    __builtin_amdgcn_global_load_lds((const __attribute__((address_space(1))) void*)g,
                                     (__attribute__((address_space(3))) void*)l, 16, 0, 0);
}

// ---------------- phase A: softmax+replicate (fp32 out x8 + bf16) + converts ----------------
__global__ __launch_bounds__(256) void phaseA(
    const float* __restrict__ posi, float* __restrict__ attn_out,
    unsigned short* __restrict__ a_bf,
    const float* __restrict__ v, const float* __restrict__ wv, const float* __restrict__ wfc,
    unsigned short* __restrict__ v_bf, unsigned short* __restrict__ wv_bf,
    unsigned short* __restrict__ wfc_bf) {
    __shared__ float red[8];
    const int bid = blockIdx.x;
    const int t = threadIdx.x;
    if (bid < 16384) {
        const int h = bid >> 10, i = bid & 1023;
        const float4* rowp = (const float4*)(posi + (((size_t)h << 10) + i) * 1024);
        float4 p = rowp[t];
        const int j0 = t << 2;
        float* pf = (float*)&p;
        if (i >= j0 && i < j0 + 4) pf[i - j0] = -1e30f;  // mask diagonal
        float m = fmaxf(fmaxf(pf[0], pf[1]), fmaxf(pf[2], pf[3]));
        m = waveMax(m);
        if ((t & 63) == 0) red[t >> 6] = m;
        __syncthreads();
        m = fmaxf(fmaxf(red[0], red[1]), fmaxf(red[2], red[3]));
        const float e0 = __expf(pf[0] - m), e1 = __expf(pf[1] - m);
        const float e2 = __expf(pf[2] - m), e3 = __expf(pf[3] - m);
        float s = waveSum(e0 + e1 + e2 + e3);
        if ((t & 63) == 0) red[4 + (t >> 6)] = s;
        __syncthreads();
        s = red[4] + red[5] + red[6] + red[7];
        const float inv = 1.0f / s;
        f32x4 a;
        a[0] = e0 * inv; a[1] = e1 * inv; a[2] = e2 * inv; a[3] = e3 * inv;
        float* base = attn_out + (((size_t)(h << 3)) << 20) + ((size_t)i << 10);
#pragma unroll
        for (int b = 0; b < 8; ++b)
            __builtin_nontemporal_store(a, (f32x4*)(base + ((size_t)b << 20)) + t);
        short4v u;
        u[0] = (short)f2bf(a[0]); u[1] = (short)f2bf(a[1]);
        u[2] = (short)f2bf(a[2]); u[3] = (short)f2bf(a[3]);
        *(short4v*)(a_bf + ((((size_t)h << 10) + i) << 10) + j0) = u;
    } else {
        int b = bid - 16384;
        const float* src;
        unsigned short* dst;
        if (b < 8192)      { src = v;   dst = v_bf; }
        else if (b < 9216) { src = wv;  dst = wv_bf;  b -= 8192; }
        else               { src = wfc; dst = wfc_bf; b -= 9216; }
        const size_t idx = ((size_t)b * 256 + t) << 2;
        const float4 x = *(const float4*)(src + idx);
        short4v u;
        u[0] = (short)f2bf(x.x); u[1] = (short)f2bf(x.y);
        u[2] = (short)f2bf(x.z); u[3] = (short)f2bf(x.w);
        *(short4v*)(dst + idx) = u;
    }
}

// ---------------- 128x128 MFMA GEMM core, BK=64 dbuf, 8 WAVES (4/SIMD) ----------------
// r9 schedule, twice the waves: 16 rounds x { barrierA; stage t+1 (4 gloads/wave);
// vmcnt(4); barrierB; 2 ksubs x (6 ds_read_b128 + 8 MFMA) }. Wave w: output slab
// (wr=w>>2)*64 rows x (wc=w&3)*32 cols; acc[4][2].
template <int EPI>
static __device__ __forceinline__ void gemm128_core(
    const unsigned short* __restrict__ A,
    const unsigned short* __restrict__ Bt,
    const float* __restrict__ bias,
    void* __restrict__ Cout,
    const int K, const int tm, const int tn, const int bh,
    unsigned short* sA, unsigned short* sB) {  // each 2*8192 shorts (32KB)
    const int tid = threadIdx.x;   // < 512
    const int lane = tid & 63;
    const int w = tid >> 6;        // 0..7
    const int wr = w >> 2;         // 0..1  (64-row slab)
    const int wc = w & 3;          // 0..3  (32-col slab)

    const unsigned short* Ab = A + (size_t)tm * 128 * K;
    const unsigned short* Bb = Bt + (size_t)tn * 128 * K;

    const int lrow = lane >> 3;    // 0..7
    const int lch = lane & 7;      // 16B chunk of a 128B row

    // fragment ds_read offsets (shorts), per ksub
    int offA[2][4], offB[2][2];
#pragma unroll
    for (int ks = 0; ks < 2; ++ks) {
#pragma unroll
        for (int f = 0; f < 4; ++f) {
            const int fra = wr * 64 + f * 16 + (lane & 15);
            offA[ks][f] = fra * 64 + ((ks * 4 + (lane >> 4)) ^ (fra & 7)) * 8;
        }
#pragma unroll
        for (int j = 0; j < 2; ++j) {
            const int frb = wc * 32 + j * 16 + (lane & 15);
            offB[ks][j] = frb * 64 + ((ks * 4 + (lane >> 4)) ^ (frb & 7)) * 8;
        }
    }

    f32x4 acc[4][2];
#pragma unroll
    for (int i = 0; i < 4; ++i)
#pragma unroll
        for (int j = 0; j < 2; ++j) acc[i][j] = (f32x4){0.f, 0.f, 0.f, 0.f};

    const int nst = K >> 6;  // 16 rounds

    // wave w stages A rows [w*16, w*16+16) and B rows [w*16, w*16+16): 2+2 gloads
#define STAGE64(buf, kt)                                                          \
    {                                                                             \
        unsigned short* dA = sA + ((buf) << 13);                                  \
        unsigned short* dB = sB + ((buf) << 13);                                  \
        _Pragma("unroll")                                                         \
        for (int g = 0; g < 2; ++g) {                                             \
            const int row = w * 16 + g * 8 + lrow;                                \
            const int sc = ((lch ^ (row & 7)) << 3);                              \
            gload_lds16(Ab + (size_t)row * K + (kt) + sc, dA + (w * 16 + g * 8) * 64); \
            gload_lds16(Bb + (size_t)row * K + (kt) + sc, dB + (w * 16 + g * 8) * 64); \
        }                                                                         \
    }

    STAGE64(0, 0)

    for (int t = 0; t < nst; ++t) {
        __builtin_amdgcn_s_barrier();            // A: all waves done computing round t-1
        __builtin_amdgcn_sched_barrier(0);
        if (t + 1 < nst) {
            STAGE64((t + 1) & 1, (t + 1) << 6)
            asm volatile("s_waitcnt vmcnt(4)" ::: "memory");  // own stage t landed; t+1 flying
        } else {
            asm volatile("s_waitcnt vmcnt(0)" ::: "memory");
        }
        __builtin_amdgcn_s_barrier();            // B: everyone's stage t visible
        __builtin_amdgcn_sched_barrier(0);
        const unsigned short* bA = sA + ((t & 1) << 13);
        const unsigned short* bB = sB + ((t & 1) << 13);
#pragma unroll
        for (int ks = 0; ks < 2; ++ks) {
            short8 af[4], bfv[2];
#pragma unroll
            for (int f = 0; f < 4; ++f) af[f] = *(const short8*)&bA[offA[ks][f]];
#pragma unroll
            for (int j = 0; j < 2; ++j) bfv[j] = *(const short8*)&bB[offB[ks][j]];
            __builtin_amdgcn_s_setprio(1);
#pragma unroll
            for (int i = 0; i < 4; ++i)
#pragma unroll
                for (int j = 0; j < 2; ++j)
                    acc[i][j] = __builtin_amdgcn_mfma_f32_16x16x32_bf16(af[i], bfv[j], acc[i][j], 0, 0, 0);
            __builtin_amdgcn_s_setprio(0);
        }
    }
#undef STAGE64

#pragma unroll
    for (int i = 0; i < 4; ++i) {
        const int gRow0 = tm * 128 + wr * 64 + i * 16 + ((lane >> 4) << 2);
#pragma unroll
        for (int j = 0; j < 2; ++j) {
            const int gCol = tn * 128 + wc * 32 + j * 16 + (lane & 15);
            f32x4 v = acc[i][j];
            if (EPI == 1) {
                const float bb2 = bias[gCol];
                const int hh = gCol >> 6, dd = gCol & 63;
                const int b = gRow0 >> 10, ll2 = gRow0 & 1023;
                unsigned short* C = (unsigned short*)Cout;
                short4v u;
                u[0] = (short)f2bf(v[0] + bb2);
                u[1] = (short)f2bf(v[1] + bb2);
                u[2] = (short)f2bf(v[2] + bb2);
                u[3] = (short)f2bf(v[3] + bb2);
                *(short4v*)(C + (size_t)hh * 524288 + ((size_t)b * 64 + dd) * 1024 + ll2) = u;
            } else if (EPI == 2) {
                const int b = gCol >> 6, dd = gCol & 63;
                unsigned short* X = (unsigned short*)Cout;
#pragma unroll
                for (int r = 0; r < 4; ++r)
                    X[((size_t)b * 1024 + gRow0 + r) * 1024 + bh * 64 + dd] = f2bf(v[r]);
            } else {
                const float bb2 = bias[gCol];
                float* O = (float*)Cout;
#pragma unroll
                for (int r = 0; r < 4; ++r)
                    O[(size_t)(gRow0 + r) * 1024 + gCol] = v[r] + bb2;
            }
        }
    }
}

// ---------------- GEMM wrappers (XCD-swizzled block id, 512 = 8 x 64; 512 threads) ----------------
__global__ __launch_bounds__(512) void gemm_k1(const unsigned short* __restrict__ A,
                                               const unsigned short* __restrict__ Bt,
                                               const float* __restrict__ bias,
                                               unsigned short* __restrict__ C) {
    __shared__ unsigned short sA[16384], sB[16384];
    const int s = (blockIdx.x & 7) * 64 + (blockIdx.x >> 3);
    gemm128_core<1>(A, Bt, bias, C, 1024, s >> 3, s & 7, 0, sA, sB);
}

__global__ __launch_bounds__(512) void gemm_k2(const unsigned short* __restrict__ A,
                                               const unsigned short* __restrict__ Bt,
                                               unsigned short* __restrict__ X) {
    __shared__ unsigned short sA[16384], sB[16384];
    const int s = (blockIdx.x & 7) * 64 + (blockIdx.x >> 3);
    const int bh = s >> 5;
    gemm128_core<2>(A + (size_t)bh * 1048576, Bt + (size_t)bh * 524288, nullptr, X,
                    1024, (s >> 2) & 7, s & 3, bh, sA, sB);
}

__global__ __launch_bounds__(512) void gemm_k3(const unsigned short* __restrict__ A,
                                               const unsigned short* __restrict__ Bt,
                                               const float* __restrict__ bias,
                                               float* __restrict__ O) {
    __shared__ unsigned short sA[16384], sB[16384];
    const int s = (blockIdx.x & 7) * 64 + (blockIdx.x >> 3);
    gemm128_core<3>(A, Bt, bias, O, 1024, s >> 3, s & 7, 0, sA, sB);
}

// ---------------- in-place row LayerNorm over DM=1024 ----------------
__global__ __launch_bounds__(256) void ln_kernel(float* __restrict__ out,
                                                 const float* __restrict__ g,
                                                 const float* __restrict__ b) {
    __shared__ float red[8];
    const int row = blockIdx.x, t = threadIdx.x;
    float4* p = (float4*)(out + ((size_t)row << 10));
    float4 x = p[t];
    float s = x.x + x.y + x.z + x.w;
    float sq = x.x * x.x + x.y * x.y + x.z * x.z + x.w * x.w;
    s = waveSum(s);
    sq = waveSum(sq);
    if ((t & 63) == 0) { red[t >> 6] = s; red[4 + (t >> 6)] = sq; }
    __syncthreads();
    s = red[0] + red[1] + red[2] + red[3];
    sq = red[4] + red[5] + red[6] + red[7];
    const float mu = s * (1.f / 1024.f);
    const float var = sq * (1.f / 1024.f) - mu * mu;
    const float rinv = rsqrtf(var + 1e-5f);
    const float4 gg = ((const float4*)g)[t];
    const float4 bb = ((const float4*)b)[t];
    x.x = (x.x - mu) * rinv * gg.x + bb.x;
    x.y = (x.y - mu) * rinv * gg.y + bb.y;
    x.z = (x.z - mu) * rinv * gg.z + bb.z;
    x.w = (x.w - mu) * rinv * gg.w + bb.w;
    p[t] = x;
}

extern "C" void kernel_launch(void* const* d_in, const int* in_sizes, int n_in,
                              void* d_out, int out_size, void* d_ws, size_t ws_size,
                              hipStream_t stream) {
    const float* v    = (const float*)d_in[2];
    const float* posi = (const float*)d_in[3];
    const float* w_v  = (const float*)d_in[6];
    const float* b_v  = (const float*)d_in[7];
    const float* w_fc = (const float*)d_in[8];
    const float* b_fc = (const float*)d_in[9];
    const float* ln_g = (const float*)d_in[10];
    const float* ln_b = (const float*)d_in[11];

    float* out = (float*)d_out;                     // [8,1024,1024] fp32
    float* attn_out = out + (size_t)NB * NL * NDM;  // [128,1024,1024] fp32

    char* ws = (char*)d_ws;
    unsigned short* A_bf   = (unsigned short*)(ws);              // [16][1024][1024] bf16  32MB
    unsigned short* v_bf   = (unsigned short*)(ws + 33554432);   // [8192][1024]     bf16  16MB
    unsigned short* wv_bf  = (unsigned short*)(ws + 50331648);   // [1024][1024]     bf16   2MB
    unsigned short* wfc_bf = (unsigned short*)(ws + 52428800);   // [1024][1024]     bf16   2MB
    unsigned short* vvT    = (unsigned short*)(ws + 54525952);   // [16][512][1024]  bf16  16MB
    unsigned short* X      = (unsigned short*)(ws + 71303168);   // [8192][1024]     bf16  16MB

    // softmax -> attn fp32 (x8, nontemporal) + A_bf, plus bf16 converts
    phaseA<<<26624, 256, 0, stream>>>(posi, attn_out, A_bf, v, w_v, w_fc, v_bf, wv_bf, wfc_bf);
    // gemm1: vvT[h][b*64+d][l] = (v@w_v^T+b_v)^T
    gemm_k1<<<512, 512, 0, stream>>>(v_bf, wv_bf, b_v, vvT);
    // gemm2: X[(b*1024+q)][h*64+d] = A[h]@vvT[h]^T
    gemm_k2<<<512, 512, 0, stream>>>(A_bf, vvT, X);
    // gemm3: out = X@w_fc^T + b_fc (fp32)
    gemm_k3<<<512, 512, 0, stream>>>(X, wfc_bf, b_fc, out);
    ln_kernel<<<8192, 256, 0, stream>>>(out, ln_g, ln_b);
}